// Round 10
// baseline (7032.819 us; speedup 1.0000x reference)
//
#include <hip/hip_runtime.h>
#include <math.h>

namespace {
constexpr int B_ = 128;
constexpr int T_ = 256;
constexpr int D_ = 512;
constexpr int U_ = 1024;
constexpr int N3U = 3 * U_;        // 3072
constexpr int K_TOT = D_ + U_;     // 1536
constexpr int NBLK = 64;           // u-tiles (16 u each), 1 block/CU
constexpr int NW = 4;              // waves per block = independent chains (32 b each)
constexpr int WROWS = 48;          // 3 gates x 16 u
constexpr int ROWB = 3088;         // LDS row stride bytes: (1536+8)*2
constexpr int LDS_BYTES = WROWS * ROWB;  // 148224
constexpr int POLL_LIM = 1 << 20;
}

#define E_CONST 2.71828182845904523536f

using bf16x8 = __attribute__((ext_vector_type(8))) short;
using f32x4  = __attribute__((ext_vector_type(4))) float;

__device__ inline unsigned short f2bf(float f) {
    union { float f; unsigned int u; } a; a.f = f;
    unsigned int u = a.u;
    return (unsigned short)((u + 0x7FFFu + ((u >> 16) & 1u)) >> 16);  // RNE
}

__device__ inline bf16x8 cvt8(const float* src) {
    float v[8];
    *reinterpret_cast<float4*>(&v[0]) = *reinterpret_cast<const float4*>(src);
    *reinterpret_cast<float4*>(&v[4]) = *reinterpret_cast<const float4*>(src + 4);
    bf16x8 r;
    #pragma unroll
    for (int j = 0; j < 8; ++j) r[j] = (short)f2bf(v[j]);
    return r;
}

// Issue 8 coherent (L1/L2-bypass, L3-served) 16B loads at base + G*512 + j*64.
#define ISSUE8(arr, base, G)                                                   \
    {                                                                          \
        _Pragma("unroll")                                                      \
        for (int j = 0; j < 8; ++j) {                                          \
            asm volatile("global_load_dwordx4 %0, %1, off offset:%2 sc0 sc1"   \
                         : "=&v"(arr[j])                                       \
                         : "v"(base), "i"((G) * 512 + j * 64));                \
        }                                                                      \
    }

// Re-def each value AFTER the preceding waitcnt so MFMAs can't hoist above it.
#define PIN8(arr)                                                              \
    {                                                                          \
        _Pragma("unroll")                                                      \
        for (int j = 0; j < 8; ++j) asm volatile("" : "+v"(arr[j]));           \
    }

#define WAITV(N) asm volatile("s_waitcnt vmcnt(" #N ")" ::: "memory")

// ---- one-time prep: WcatT[n][k] = bf16( k<512 ? Wk[k][n] : Wr[k-512][n] ) ----
__global__ void wprep(const float* __restrict__ Wk, const float* __restrict__ Wr,
                      unsigned short* __restrict__ WcatT) {
    __shared__ unsigned short S[32][33];
    const int kb = blockIdx.x * 32;
    const int nb = blockIdx.y * 32;
    const int tx = threadIdx.x;
    const int ty = threadIdx.y;
    #pragma unroll
    for (int j = 0; j < 4; ++j) {
        const int r = ty + 8 * j;
        const int k = kb + r;
        const int n = nb + tx;
        const float v = (k < D_) ? Wk[(size_t)k * N3U + n]
                                 : Wr[(size_t)(k - D_) * N3U + n];
        S[tx][r] = f2bf(v);
    }
    __syncthreads();
    #pragma unroll
    for (int j = 0; j < 4; ++j) {
        const int r = ty + 8 * j;
        WcatT[(size_t)(nb + r) * K_TOT + kb + tx] = S[r][tx];
    }
}

// ---- one-time prep: decays[b][t] = 1/log(e + dt) ----
__global__ void dprep(const float* __restrict__ dts, float* __restrict__ decays) {
    const int i = blockIdx.x * 256 + threadIdx.x;
    if (i < B_ * T_) decays[i] = 1.0f / logf(E_CONST + dts[i]);
}

// ---- persistent kernel: 64 blocks x 4 free-running chain-waves ----
// Block = one 16-u tile, weights LDS-resident. Wave w = chain for batches
// [32w, 32w+32): 3 gates x 2 b-tiles, in-wave epilogue, per-(w,block) flag.
// NO barriers in the t-loop; chains overlap each other's sync latency.
__global__ __launch_bounds__(256) void tgru_chains(
    const float* __restrict__ seq,            // [B,T,D] fp32
    const float* __restrict__ decays,         // [B,T] fp32
    const unsigned short* __restrict__ WcatT, // [3072][1536] bf16
    const float* __restrict__ ib,             // [3U]
    const float* __restrict__ rb,             // [3U]
    unsigned short* hbA,                      // h*dec bf16 (h at even t)
    unsigned short* hbB,                      // h at odd t
    unsigned int* flags,                      // [NW*64] x 16 u32 (64B lines)
    float* __restrict__ out)                  // [B,U]
{
    extern __shared__ char lds[];

    const int tid  = threadIdx.x;
    const int lane = tid & 63;
    const int w    = tid >> 6;     // chain id 0..3
    const int l15  = lane & 15;
    const int lk   = lane >> 4;
    const int ub   = blockIdx.x;   // u-tile
    const int u0   = ub * 16;
    const int u    = u0 + l15;

    // ---- stage weights: 48 rows x 1536 k into LDS (padded rows), once ----
    for (int idx = tid; idx < WROWS * 192; idx += 256) {
        const int c = idx / 192;          // row 0..47
        const int o = idx % 192;          // 16B chunk
        const unsigned short* src =
            WcatT + (size_t)((c >> 4) * U_ + u0 + (c & 15)) * K_TOT + o * 8;
        *reinterpret_cast<bf16x8*>(lds + (size_t)c * ROWB + o * 16) =
            *reinterpret_cast<const bf16x8*>(src);
    }
    __syncthreads();   // the ONLY block-wide barrier

    // weight fragment base pointers (per lane, shared by both b-tiles)
    const char* wz = lds + (size_t)(0  + l15) * ROWB + 16 * lk;
    const char* wr = lds + (size_t)(16 + l15) * ROWB + 16 * lk;
    const char* wh = lds + (size_t)(32 + l15) * ROWB + 16 * lk;

    // per-lane epilogue constants (all outputs of a lane share column u)
    const float bzs  = ib[u] + rb[u];
    const float brs  = ib[U_ + u] + rb[U_ + u];
    const float ibh_ = ib[2 * U_ + u];
    const float rbh_ = rb[2 * U_ + u];

    float hreg[2][4] = {{0.f,0.f,0.f,0.f},{0.f,0.f,0.f,0.f}};  // fp32 h*dec
    unsigned int* myflag = flags + (w * 64 + ub) * 16;
    const unsigned int* pollp = flags + (w * 64 + lane) * 16;  // lane polls block 'lane'

    #pragma unroll 1
    for (int t = 0; t < T_; ++t) {
        const unsigned short* hbp = (t & 1) ? hbB : hbA;   // h(t)
        unsigned short*       hbn = (t & 1) ? hbA : hbB;   // h(t+1)

        f32x4 az[2], ar[2], ahx[2], ahr[2];
        #pragma unroll
        for (int bt = 0; bt < 2; ++bt) {
            az[bt] = {0.f,0.f,0.f,0.f}; ar[bt] = {0.f,0.f,0.f,0.f};
            ahx[bt] = {0.f,0.f,0.f,0.f}; ahr[bt] = {0.f,0.f,0.f,0.f};
        }

        // ---- x-phase (k in [0,512)) — independent of other blocks ----
        #pragma unroll
        for (int bt = 0; bt < 2; ++bt) {
            const int b = 32 * w + 16 * bt + l15;
            const float* ap = seq + ((size_t)b * T_ + t) * D_ + 8 * lk;
            #pragma unroll 4
            for (int ks = 0; ks < 16; ++ks) {
                const bf16x8 a = cvt8(ap + 32 * ks);
                az[bt]  = __builtin_amdgcn_mfma_f32_16x16x32_bf16(
                    a, *reinterpret_cast<const bf16x8*>(wz + 64 * ks), az[bt], 0, 0, 0);
                ar[bt]  = __builtin_amdgcn_mfma_f32_16x16x32_bf16(
                    a, *reinterpret_cast<const bf16x8*>(wr + 64 * ks), ar[bt], 0, 0, 0);
                ahx[bt] = __builtin_amdgcn_mfma_f32_16x16x32_bf16(
                    a, *reinterpret_cast<const bf16x8*>(wh + 64 * ks), ahx[bt], 0, 0, 0);
            }
        }

        if (t > 0) {
            // ---- poll this chain's 64 producer flags (one lane each) ----
            int guard = 0;
            for (;;) {
                const unsigned int v = __hip_atomic_load(
                    pollp, __ATOMIC_RELAXED, __HIP_MEMORY_SCOPE_AGENT);
                if (__all((int)(v >= (unsigned int)t))) break;
                if (++guard > POLL_LIM) break;   // safety: no hang
            }
            // (poll load drained vmcnt to 0; counted waits below are exact)

            // ---- h-phase (k in [512,1536)): batched coherent loads ----
            #pragma unroll
            for (int bt = 0; bt < 2; ++bt) {
                const int b = 32 * w + 16 * bt + l15;
                const char* hbase = (const char*)(hbp + (size_t)b * U_ + 8 * lk);
                bf16x8 h0[8], h1[8], h2[8], h3[8];
                ISSUE8(h0, hbase, 0)
                ISSUE8(h1, hbase, 1)
                ISSUE8(h2, hbase, 2)
                ISSUE8(h3, hbase, 3)

                WAITV(24); PIN8(h0)
                #pragma unroll
                for (int j = 0; j < 8; ++j) {
                    const int o = 1024 + 64 * (0 * 8 + j);
                    az[bt]  = __builtin_amdgcn_mfma_f32_16x16x32_bf16(
                        h0[j], *reinterpret_cast<const bf16x8*>(wz + o), az[bt], 0, 0, 0);
                    ar[bt]  = __builtin_amdgcn_mfma_f32_16x16x32_bf16(
                        h0[j], *reinterpret_cast<const bf16x8*>(wr + o), ar[bt], 0, 0, 0);
                    ahr[bt] = __builtin_amdgcn_mfma_f32_16x16x32_bf16(
                        h0[j], *reinterpret_cast<const bf16x8*>(wh + o), ahr[bt], 0, 0, 0);
                }
                WAITV(16); PIN8(h1)
                #pragma unroll
                for (int j = 0; j < 8; ++j) {
                    const int o = 1024 + 64 * (1 * 8 + j);
                    az[bt]  = __builtin_amdgcn_mfma_f32_16x16x32_bf16(
                        h1[j], *reinterpret_cast<const bf16x8*>(wz + o), az[bt], 0, 0, 0);
                    ar[bt]  = __builtin_amdgcn_mfma_f32_16x16x32_bf16(
                        h1[j], *reinterpret_cast<const bf16x8*>(wr + o), ar[bt], 0, 0, 0);
                    ahr[bt] = __builtin_amdgcn_mfma_f32_16x16x32_bf16(
                        h1[j], *reinterpret_cast<const bf16x8*>(wh + o), ahr[bt], 0, 0, 0);
                }
                WAITV(8); PIN8(h2)
                #pragma unroll
                for (int j = 0; j < 8; ++j) {
                    const int o = 1024 + 64 * (2 * 8 + j);
                    az[bt]  = __builtin_amdgcn_mfma_f32_16x16x32_bf16(
                        h2[j], *reinterpret_cast<const bf16x8*>(wz + o), az[bt], 0, 0, 0);
                    ar[bt]  = __builtin_amdgcn_mfma_f32_16x16x32_bf16(
                        h2[j], *reinterpret_cast<const bf16x8*>(wr + o), ar[bt], 0, 0, 0);
                    ahr[bt] = __builtin_amdgcn_mfma_f32_16x16x32_bf16(
                        h2[j], *reinterpret_cast<const bf16x8*>(wh + o), ahr[bt], 0, 0, 0);
                }
                WAITV(0); PIN8(h3)
                #pragma unroll
                for (int j = 0; j < 8; ++j) {
                    const int o = 1024 + 64 * (3 * 8 + j);
                    az[bt]  = __builtin_amdgcn_mfma_f32_16x16x32_bf16(
                        h3[j], *reinterpret_cast<const bf16x8*>(wz + o), az[bt], 0, 0, 0);
                    ar[bt]  = __builtin_amdgcn_mfma_f32_16x16x32_bf16(
                        h3[j], *reinterpret_cast<const bf16x8*>(wr + o), ar[bt], 0, 0, 0);
                    ahr[bt] = __builtin_amdgcn_mfma_f32_16x16x32_bf16(
                        h3[j], *reinterpret_cast<const bf16x8*>(wh + o), ahr[bt], 0, 0, 0);
                }
            }
        }

        // ---- in-wave epilogue: gates, blend, publish ----
        #pragma unroll
        for (int bt = 0; bt < 2; ++bt) {
            #pragma unroll
            for (int q = 0; q < 4; ++q) {
                const int b = 32 * w + 16 * bt + 4 * lk + q;
                const float z  = 1.0f / (1.0f + expf(-(az[bt][q] + bzs)));
                const float r  = 1.0f / (1.0f + expf(-(ar[bt][q] + brs)));
                const float hh = tanhf(ahx[bt][q] + ibh_ + r * (ahr[bt][q] + rbh_));
                const float hn = z * hreg[bt][q] + (1.0f - z) * hh;
                if (t == T_ - 1) {
                    out[(size_t)b * U_ + u] = hn;
                } else {
                    const float hd = hn * decays[b * T_ + t + 1];
                    hreg[bt][q] = hd;
                    __hip_atomic_store(&hbn[(size_t)b * U_ + u], f2bf(hd),
                                       __ATOMIC_RELAXED, __HIP_MEMORY_SCOPE_AGENT);
                }
            }
        }

        if (t < T_ - 1) {
            WAITV(0);   // h stores landed at L3
            if (lane == 0) {
                __hip_atomic_store(myflag, (unsigned int)(t + 1),
                                   __ATOMIC_RELAXED, __HIP_MEMORY_SCOPE_AGENT);
            }
        }
    }
}

extern "C" void kernel_launch(void* const* d_in, const int* in_sizes, int n_in,
                              void* d_out, int out_size, void* d_ws, size_t ws_size,
                              hipStream_t stream) {
    const float* seq = (const float*)d_in[0];
    const float* dts = (const float*)d_in[1];
    const float* Wk  = (const float*)d_in[2];
    const float* Wr  = (const float*)d_in[3];
    const float* ib  = (const float*)d_in[4];
    const float* rb  = (const float*)d_in[5];
    float* out = (float*)d_out;

    char* wsb = (char*)d_ws;
    // ws layout (bytes):
    //   [0,        9437184)   WcatT bf16 [3072][1536]
    //   [9437184,  9568256)   decays fp32 [128][256]
    //   [9568256,  9830400)   hbA bf16 [128][1024]  (not read at t=0)
    //   [9830400, 10092544)   hbB
    //   [10092544,10108928)   flags: 4 chains x 64 blocks x 64 B
    unsigned short* wcat  = (unsigned short*)(wsb);
    float*          decays = (float*)(wsb + 9437184);
    unsigned short* hbA   = (unsigned short*)(wsb + 9568256);
    unsigned short* hbB   = (unsigned short*)(wsb + 9830400);
    unsigned int*   flags = (unsigned int*)(wsb + 10092544);

    // flags must be 0 at start of every replay (monotonic within a launch)
    hipMemsetAsync(flags, 0, 16384, stream);

    wprep<<<dim3(K_TOT / 32, N3U / 32), dim3(32, 8), 0, stream>>>(Wk, Wr, wcat);
    dprep<<<dim3((B_ * T_ + 255) / 256), dim3(256), 0, stream>>>(dts, decays);

    hipFuncSetAttribute((const void*)tgru_chains,
                        hipFuncAttributeMaxDynamicSharedMemorySize, LDS_BYTES);

    tgru_chains<<<dim3(NBLK), dim3(256), LDS_BYTES, stream>>>(
        seq, decays, wcat, ib, rb, hbA, hbB, flags, out);
}

// Round 11
// 3981.629 us; speedup vs baseline: 1.7663x; 1.7663x over previous
//
#include <hip/hip_runtime.h>
#include <math.h>

namespace {
constexpr int B_ = 128;
constexpr int T_ = 256;
constexpr int D_ = 512;
constexpr int U_ = 1024;
constexpr int N3U = 3 * U_;        // 3072
constexpr int K_TOT = D_ + U_;     // 1536
constexpr int WROWS = 48;          // 3 gates x 16 u
constexpr int ROWB = 3088;         // LDS row stride bytes: (1536+8)*2, 16B aligned
constexpr int EXCH_OFF = WROWS * ROWB;           // 148224
constexpr int LDS_BYTES = EXCH_OFF + 12288;      // 160512 (<= 163840)
constexpr unsigned SENT = 0x7FC07FC0u;           // bf16 NaN pair: unreachable for |h|<=1
constexpr int POLL_LIM = 1 << 17;
}

#define E_CONST 2.71828182845904523536f

using bf16x8 = __attribute__((ext_vector_type(8))) short;
using f32x4  = __attribute__((ext_vector_type(4))) float;
using u32x4  = __attribute__((ext_vector_type(4))) unsigned int;

__device__ inline unsigned short f2bf(float f) {
    union { float f; unsigned int u; } a; a.f = f;
    unsigned int u = a.u;
    return (unsigned short)((u + 0x7FFFu + ((u >> 16) & 1u)) >> 16);  // RNE
}

__device__ inline bf16x8 cvt8(const float* src) {
    float v[8];
    *reinterpret_cast<float4*>(&v[0]) = *reinterpret_cast<const float4*>(src);
    *reinterpret_cast<float4*>(&v[4]) = *reinterpret_cast<const float4*>(src + 4);
    bf16x8 r;
    #pragma unroll
    for (int j = 0; j < 8; ++j) r[j] = (short)f2bf(v[j]);
    return r;
}

// 16 coherent (L1/L2-bypass, L3-served) 16B loads at base + j*64 bytes.
#define ISSUE16(arr, base)                                                     \
    {                                                                          \
        _Pragma("unroll")                                                      \
        for (int j = 0; j < 16; ++j) {                                         \
            asm volatile("global_load_dwordx4 %0, %1, off offset:%2 sc0 sc1"   \
                         : "=&v"(arr[j])                                       \
                         : "v"(base), "i"(j * 64));                            \
        }                                                                      \
    }
#define PIN16(arr)                                                             \
    {                                                                          \
        _Pragma("unroll")                                                      \
        for (int j = 0; j < 16; ++j) asm volatile("" : "+v"(arr[j]));          \
    }
#define WAITV0 asm volatile("s_waitcnt vmcnt(0)" ::: "memory")
#define STORE_DW(addr, val)                                                    \
    asm volatile("global_store_dword %0, %1, off sc0 sc1"                      \
                 :: "v"(addr), "v"(val) : "memory")

// ---- one-time prep: WcatT[n][k] = bf16( k<512 ? Wk[k][n] : Wr[k-512][n] ) ----
__global__ void wprep(const float* __restrict__ Wk, const float* __restrict__ Wr,
                      unsigned short* __restrict__ WcatT) {
    __shared__ unsigned short S[32][33];
    const int kb = blockIdx.x * 32;
    const int nb = blockIdx.y * 32;
    const int tx = threadIdx.x;
    const int ty = threadIdx.y;
    #pragma unroll
    for (int j = 0; j < 4; ++j) {
        const int r = ty + 8 * j;
        const int k = kb + r;
        const int n = nb + tx;
        const float v = (k < D_) ? Wk[(size_t)k * N3U + n]
                                 : Wr[(size_t)(k - D_) * N3U + n];
        S[tx][r] = f2bf(v);
    }
    __syncthreads();
    #pragma unroll
    for (int j = 0; j < 4; ++j) {
        const int r = ty + 8 * j;
        WcatT[(size_t)(nb + r) * K_TOT + kb + tx] = S[r][tx];
    }
}

// ---- one-time prep: decays + poison all 3 h buffers ----
__global__ void dprep(const float* __restrict__ dts, float* __restrict__ decays,
                      unsigned int* __restrict__ bufs /* 3*64K dwords */) {
    const int i = blockIdx.x * 256 + threadIdx.x;
    if (i < B_ * T_) decays[i] = 1.0f / logf(E_CONST + dts[i]);
    for (int j = i; j < 3 * B_ * U_ / 2; j += 256 * 384) bufs[j] = SENT;
}

// ---- persistent kernel: sentinel-data-poll, 3-buffer rotation ----
// 256 blocks (XCD-clustered groups), 384 thr = 6 waves = 2 bt x 3 kslices.
// ks0 wave: x-GEMM (K 0..512, 3 gates) + epilogue + poison + publish.
// ks1/ks2 waves: gather-poll h u-half, 3-gate partial GEMM, exf exchange.
__global__ __launch_bounds__(384) void tgru_sent(
    const float* __restrict__ seq,            // [B,T,D] fp32
    const float* __restrict__ decays,         // [B,T]
    const unsigned short* __restrict__ WcatT, // [3072][1536] bf16
    const float* __restrict__ ib,             // [3U]
    const float* __restrict__ rb,             // [3U]
    unsigned short* hb0, unsigned short* hb1, unsigned short* hb2,
    float* __restrict__ out)                  // [B,U]
{
    extern __shared__ char lds[];

    const int tid  = threadIdx.x;
    const int lane = tid & 63;
    const int w    = tid >> 6;     // 0..5
    const int bt   = w & 1;
    const int ks   = w >> 1;       // 0 = x/epilogue, 1/2 = h halves
    const int l15  = lane & 15;
    const int lk   = lane >> 4;
    const int bid  = blockIdx.x;
    const int bg   = (bid >> 1) & 3;                 // XCD-clustered group
    const int ub   = ((bid >> 3) << 1) | (bid & 1);  // 0..63
    const int u0   = ub * 16;
    const int u    = u0 + l15;
    const int b_base = bg * 32 + bt * 16;

    // ---- stage weights: 48 rows x 1536 k into LDS, once ----
    for (int idx = tid; idx < WROWS * 192; idx += 384) {
        const int c = idx / 192;
        const int o = idx % 192;
        const unsigned short* src =
            WcatT + (size_t)((c >> 4) * U_ + u0 + (c & 15)) * K_TOT + o * 8;
        *reinterpret_cast<bf16x8*>(lds + (size_t)c * ROWB + o * 16) =
            *reinterpret_cast<const bf16x8*>(src);
    }
    __syncthreads();

    const char* wz = lds + (size_t)(0  + l15) * ROWB + 16 * lk;
    const char* wr = lds + (size_t)(16 + l15) * ROWB + 16 * lk;
    const char* wh = lds + (size_t)(32 + l15) * ROWB + 16 * lk;

    unsigned short* bufs[3] = {hb0, hb1, hb2};

    // ks0-wave epilogue constants + register h state
    float bzs = 0.f, brs = 0.f, ibh_ = 0.f, rbh_ = 0.f;
    float hreg[4] = {0.f, 0.f, 0.f, 0.f};
    if (ks == 0) {
        bzs  = ib[u] + rb[u];
        brs  = ib[U_ + u] + rb[U_ + u];
        ibh_ = ib[2 * U_ + u];
        rbh_ = rb[2 * U_ + u];
    }

    #pragma unroll 1
    for (int t = 0; t < T_; ++t) {
        const unsigned short* gbuf = bufs[t % 3];        // h(t)
        unsigned short*       pbuf = bufs[(t + 1) % 3];  // h(t+1) target
        unsigned short*       obuf = bufs[(t + 2) % 3];  // poison target

        f32x4 az = {0.f,0.f,0.f,0.f}, ar = {0.f,0.f,0.f,0.f}, ah = {0.f,0.f,0.f,0.f};
        float decn[4];

        if (ks == 0) {
            // x-GEMM: K in [0,512), all 3 gates (seq read once per bt)
            const float* ap = seq + ((size_t)(b_base + l15) * T_ + t) * D_ + 8 * lk;
            #pragma unroll 4
            for (int j = 0; j < 16; ++j) {
                const bf16x8 a = cvt8(ap + 32 * j);
                az = __builtin_amdgcn_mfma_f32_16x16x32_bf16(
                    a, *reinterpret_cast<const bf16x8*>(wz + 64 * j), az, 0, 0, 0);
                ar = __builtin_amdgcn_mfma_f32_16x16x32_bf16(
                    a, *reinterpret_cast<const bf16x8*>(wr + 64 * j), ar, 0, 0, 0);
                ah = __builtin_amdgcn_mfma_f32_16x16x32_bf16(
                    a, *reinterpret_cast<const bf16x8*>(wh + 64 * j), ah, 0, 0, 0);
            }
            const int tn = (t < T_ - 1) ? t + 1 : t;
            #pragma unroll
            for (int q = 0; q < 4; ++q)
                decn[q] = decays[(b_base + 4 * lk + q) * T_ + tn];
        } else {
            if (t > 0) {
                // gather-poll h(t) slice: rows b_base..+16, u in [(ks-1)*512, ks*512)
                const char* hbase = (const char*)(gbuf
                    + (size_t)(b_base + l15) * U_ + (ks - 1) * 512 + 8 * lk);
                bf16x8 hv[16];
                int guard = 0;
                for (;;) {
                    ISSUE16(hv, hbase)
                    WAITV0; PIN16(hv)
                    int un = 0;
                    #pragma unroll
                    for (int j = 0; j < 16; ++j) {
                        const u32x4 d = __builtin_bit_cast(u32x4, hv[j]);
                        un |= (d[0] == SENT) | (d[1] == SENT) |
                              (d[2] == SENT) | (d[3] == SENT);
                    }
                    if (!__any(un)) break;
                    if (++guard > POLL_LIM) break;   // safety: no hang
                }
                // 3-gate partial GEMM over this u-half
                #pragma unroll 4
                for (int j = 0; j < 16; ++j) {
                    const int o = 1024 * ks + 64 * j;
                    az = __builtin_amdgcn_mfma_f32_16x16x32_bf16(
                        hv[j], *reinterpret_cast<const bf16x8*>(wz + o), az, 0, 0, 0);
                    ar = __builtin_amdgcn_mfma_f32_16x16x32_bf16(
                        hv[j], *reinterpret_cast<const bf16x8*>(wr + o), ar, 0, 0, 0);
                    ah = __builtin_amdgcn_mfma_f32_16x16x32_bf16(
                        hv[j], *reinterpret_cast<const bf16x8*>(wh + o), ah, 0, 0, 0);
                }
            }
            // exchange partials
            char* e = lds + EXCH_OFF + (size_t)((bt * 2 + (ks - 1)) * 3) * 1024;
            *reinterpret_cast<f32x4*>(e + 0 * 1024 + lane * 16) = az;
            *reinterpret_cast<f32x4*>(e + 1 * 1024 + lane * 16) = ar;
            *reinterpret_cast<f32x4*>(e + 2 * 1024 + lane * 16) = ah;
        }

        __syncthreads();   // B2: partials ready

        f32x4 sz, sr, sh;
        if (ks == 0) {
            const char* e0 = lds + EXCH_OFF + (size_t)((bt * 2 + 0) * 3) * 1024;
            const char* e1 = lds + EXCH_OFF + (size_t)((bt * 2 + 1) * 3) * 1024;
            sz = *reinterpret_cast<const f32x4*>(e0 + 0 * 1024 + lane * 16)
               + *reinterpret_cast<const f32x4*>(e1 + 0 * 1024 + lane * 16);
            sr = *reinterpret_cast<const f32x4*>(e0 + 1 * 1024 + lane * 16)
               + *reinterpret_cast<const f32x4*>(e1 + 1 * 1024 + lane * 16);
            sh = *reinterpret_cast<const f32x4*>(e0 + 2 * 1024 + lane * 16)
               + *reinterpret_cast<const f32x4*>(e1 + 2 * 1024 + lane * 16);
        }

        __syncthreads();   // B3: exf free for next step's writers

        if (ks == 0) {
            // poison own tile of obuf (next-next buffer) — safe: h(t) complete
            // implies all readers of h(t-1) (= obuf's old contents) are done.
            if (t < T_ - 1 && (lane & 1) == 0) {
                #pragma unroll
                for (int q = 0; q < 4; ++q) {
                    unsigned int* pa = (unsigned int*)(obuf
                        + (size_t)(b_base + 4 * lk + q) * U_ + u);
                    STORE_DW(pa, SENT);
                }
            }
            // epilogue
            float hn[4];
            #pragma unroll
            for (int q = 0; q < 4; ++q) {
                const float z  = 1.0f / (1.0f + expf(-(az[q] + sz[q] + bzs)));
                const float r  = 1.0f / (1.0f + expf(-(ar[q] + sr[q] + brs)));
                const float hh = tanhf(ah[q] + ibh_ + r * (sh[q] + rbh_));
                hn[q] = z * hreg[q] + (1.0f - z) * hh;
            }
            if (t == T_ - 1) {
                #pragma unroll
                for (int q = 0; q < 4; ++q)
                    out[(size_t)(b_base + 4 * lk + q) * U_ + u] = hn[q];
            } else {
                unsigned int pk[4];
                #pragma unroll
                for (int q = 0; q < 4; ++q) {
                    const float hd = hn[q] * decn[q];
                    hreg[q] = hd;
                    const float po = __shfl_xor(hd, 1);   // partner u (odd lane)
                    pk[q] = (unsigned int)f2bf(hd) | ((unsigned int)f2bf(po) << 16);
                }
                WAITV0;   // poison visible before publish becomes visible
                if ((lane & 1) == 0) {
                    #pragma unroll
                    for (int q = 0; q < 4; ++q) {
                        unsigned int* pa = (unsigned int*)(pbuf
                            + (size_t)(b_base + 4 * lk + q) * U_ + u);
                        STORE_DW(pa, pk[q]);
                    }
                }
            }
        }
    }
}

extern "C" void kernel_launch(void* const* d_in, const int* in_sizes, int n_in,
                              void* d_out, int out_size, void* d_ws, size_t ws_size,
                              hipStream_t stream) {
    const float* seq = (const float*)d_in[0];
    const float* dts = (const float*)d_in[1];
    const float* Wk  = (const float*)d_in[2];
    const float* Wr  = (const float*)d_in[3];
    const float* ib  = (const float*)d_in[4];
    const float* rb  = (const float*)d_in[5];
    float* out = (float*)d_out;

    char* wsb = (char*)d_ws;
    // ws layout (bytes):
    //   [0,        9437184)   WcatT bf16 [3072][1536]
    //   [9437184,  9568256)   decays fp32 [128][256]
    //   [9568256,  9830400)   hb0 bf16 [128][1024]
    //   [9830400, 10092544)   hb1
    //   [10092544,10354688)   hb2
    unsigned short* wcat   = (unsigned short*)(wsb);
    float*          decays = (float*)(wsb + 9437184);
    unsigned short* hb0    = (unsigned short*)(wsb + 9568256);
    unsigned short* hb1    = (unsigned short*)(wsb + 9830400);
    unsigned short* hb2    = (unsigned short*)(wsb + 10092544);

    wprep<<<dim3(K_TOT / 32, N3U / 32), dim3(32, 8), 0, stream>>>(Wk, Wr, wcat);
    // decays + poison all three h buffers (every launch/replay)
    dprep<<<dim3(384), dim3(256), 0, stream>>>(dts, decays, (unsigned int*)hb0);

    hipFuncSetAttribute((const void*)tgru_sent,
                        hipFuncAttributeMaxDynamicSharedMemorySize, LDS_BYTES);

    tgru_sent<<<dim3(256), dim3(384), LDS_BYTES, stream>>>(
        seq, decays, wcat, ib, rb, hb0, hb1, hb2, out);
}

// Round 12
// 3895.826 us; speedup vs baseline: 1.8052x; 1.0220x over previous
//
#include <hip/hip_runtime.h>
#include <math.h>

namespace {
constexpr int B_ = 128;
constexpr int T_ = 256;
constexpr int D_ = 512;
constexpr int U_ = 1024;
constexpr int N3U = 3 * U_;        // 3072
constexpr int K_TOT = D_ + U_;     // 1536
constexpr int WROWS = 48;          // 3 gates x 16 u
constexpr int ROWB = 3088;         // LDS row stride bytes: (1536+8)*2, 16B aligned
constexpr int EXCH_OFF = WROWS * ROWB;           // 148224
constexpr int LDS_BYTES = EXCH_OFF + 12288;      // 160512 (<= 163840)
constexpr unsigned SENT = 0x7FC07FC0u;           // bf16 NaN pair: unreachable for |h|<=1
constexpr int POLL_LIM = 1 << 17;
}

#define E_CONST 2.71828182845904523536f

using bf16x8 = __attribute__((ext_vector_type(8))) short;
using f32x4  = __attribute__((ext_vector_type(4))) float;
using u32x4  = __attribute__((ext_vector_type(4))) unsigned int;

__device__ inline unsigned short f2bf(float f) {
    union { float f; unsigned int u; } a; a.f = f;
    unsigned int u = a.u;
    return (unsigned short)((u + 0x7FFFu + ((u >> 16) & 1u)) >> 16);  // RNE
}

__device__ inline bf16x8 cvt8(const float* src) {
    float v[8];
    *reinterpret_cast<float4*>(&v[0]) = *reinterpret_cast<const float4*>(src);
    *reinterpret_cast<float4*>(&v[4]) = *reinterpret_cast<const float4*>(src + 4);
    bf16x8 r;
    #pragma unroll
    for (int j = 0; j < 8; ++j) r[j] = (short)f2bf(v[j]);
    return r;
}

// 16 coherent (L1/L2-bypass, L3-served) 16B loads at base + j*64 bytes.
#define ISSUE16(arr, base)                                                     \
    {                                                                          \
        _Pragma("unroll")                                                      \
        for (int j = 0; j < 16; ++j) {                                         \
            asm volatile("global_load_dwordx4 %0, %1, off offset:%2 sc0 sc1"   \
                         : "=&v"(arr[j])                                       \
                         : "v"(base), "i"(j * 64));                            \
        }                                                                      \
    }
#define PIN16(arr)                                                             \
    {                                                                          \
        _Pragma("unroll")                                                      \
        for (int j = 0; j < 16; ++j) asm volatile("" : "+v"(arr[j]));          \
    }
#define WAITV0 asm volatile("s_waitcnt vmcnt(0)" ::: "memory")
// Agent-scope store: stops/allocates at L3 (coherence point). NOT sc0 sc1 —
// system scope写通 caused 16x HBM write amplification + L3-miss gathers (R11).
#define STORE_DW_AGENT(addr, val)                                              \
    asm volatile("global_store_dword %0, %1, off sc1"                          \
                 :: "v"(addr), "v"(val) : "memory")

// ---- one-time prep: WcatT[n][k] = bf16( k<512 ? Wk[k][n] : Wr[k-512][n] ) ----
__global__ void wprep(const float* __restrict__ Wk, const float* __restrict__ Wr,
                      unsigned short* __restrict__ WcatT) {
    __shared__ unsigned short S[32][33];
    const int kb = blockIdx.x * 32;
    const int nb = blockIdx.y * 32;
    const int tx = threadIdx.x;
    const int ty = threadIdx.y;
    #pragma unroll
    for (int j = 0; j < 4; ++j) {
        const int r = ty + 8 * j;
        const int k = kb + r;
        const int n = nb + tx;
        const float v = (k < D_) ? Wk[(size_t)k * N3U + n]
                                 : Wr[(size_t)(k - D_) * N3U + n];
        S[tx][r] = f2bf(v);
    }
    __syncthreads();
    #pragma unroll
    for (int j = 0; j < 4; ++j) {
        const int r = ty + 8 * j;
        WcatT[(size_t)(nb + r) * K_TOT + kb + tx] = S[r][tx];
    }
}

// ---- one-time prep: decays + poison all 3 h buffers (every replay) ----
__global__ void dprep(const float* __restrict__ dts, float* __restrict__ decays,
                      unsigned int* __restrict__ bufs /* 3*64K dwords */) {
    const int i = blockIdx.x * 256 + threadIdx.x;
    if (i < B_ * T_) decays[i] = 1.0f / logf(E_CONST + dts[i]);
    for (int j = i; j < 3 * B_ * U_ / 2; j += 256 * 384) bufs[j] = SENT;
}

// ---- persistent kernel: sentinel-data-poll, 3-buffer rotation, sc1 stores ----
// 256 blocks (XCD-clustered groups), 384 thr = 6 waves = 2 bt x 3 kslices.
// ks0 wave: x-GEMM (K 0..512, 3 gates) + poison + epilogue + publish.
// ks1/ks2 waves: gather-poll h u-half (sentinel retry), 3-gate partial GEMM.
__global__ __launch_bounds__(384) void tgru_sent2(
    const float* __restrict__ seq,            // [B,T,D] fp32
    const float* __restrict__ decays,         // [B,T]
    const unsigned short* __restrict__ WcatT, // [3072][1536] bf16
    const float* __restrict__ ib,             // [3U]
    const float* __restrict__ rb,             // [3U]
    unsigned short* hb0, unsigned short* hb1, unsigned short* hb2,
    float* __restrict__ out)                  // [B,U]
{
    extern __shared__ char lds[];

    const int tid  = threadIdx.x;
    const int lane = tid & 63;
    const int w    = tid >> 6;     // 0..5
    const int bt   = w & 1;
    const int ks   = w >> 1;       // 0 = x/epilogue, 1/2 = h halves
    const int l15  = lane & 15;
    const int lk   = lane >> 4;
    const int bid  = blockIdx.x;
    const int bg   = (bid >> 1) & 3;                 // XCD-clustered group
    const int ub   = ((bid >> 3) << 1) | (bid & 1);  // 0..63
    const int u0   = ub * 16;
    const int u    = u0 + l15;
    const int b_base = bg * 32 + bt * 16;

    // ---- stage weights: 48 rows x 1536 k into LDS, once ----
    for (int idx = tid; idx < WROWS * 192; idx += 384) {
        const int c = idx / 192;
        const int o = idx % 192;
        const unsigned short* src =
            WcatT + (size_t)((c >> 4) * U_ + u0 + (c & 15)) * K_TOT + o * 8;
        *reinterpret_cast<bf16x8*>(lds + (size_t)c * ROWB + o * 16) =
            *reinterpret_cast<const bf16x8*>(src);
    }
    __syncthreads();

    const char* wz = lds + (size_t)(0  + l15) * ROWB + 16 * lk;
    const char* wr = lds + (size_t)(16 + l15) * ROWB + 16 * lk;
    const char* wh = lds + (size_t)(32 + l15) * ROWB + 16 * lk;

    unsigned short* bufs[3] = {hb0, hb1, hb2};

    // ks0-wave epilogue constants + register h state
    float bzs = 0.f, brs = 0.f, ibh_ = 0.f, rbh_ = 0.f;
    float hreg[4] = {0.f, 0.f, 0.f, 0.f};
    if (ks == 0) {
        bzs  = ib[u] + rb[u];
        brs  = ib[U_ + u] + rb[U_ + u];
        ibh_ = ib[2 * U_ + u];
        rbh_ = rb[2 * U_ + u];
    }

    #pragma unroll 1
    for (int t = 0; t < T_; ++t) {
        const unsigned short* gbuf = bufs[t % 3];        // h(t)
        unsigned short*       pbuf = bufs[(t + 1) % 3];  // h(t+1) target
        unsigned short*       obuf = bufs[(t + 2) % 3];  // poison target

        f32x4 az = {0.f,0.f,0.f,0.f}, ar = {0.f,0.f,0.f,0.f}, ah = {0.f,0.f,0.f,0.f};
        float decn[4];

        if (ks == 0) {
            // x-GEMM: K in [0,512), all 3 gates (seq read once per bt)
            const float* ap = seq + ((size_t)(b_base + l15) * T_ + t) * D_ + 8 * lk;
            #pragma unroll 4
            for (int j = 0; j < 16; ++j) {
                const bf16x8 a = cvt8(ap + 32 * j);
                az = __builtin_amdgcn_mfma_f32_16x16x32_bf16(
                    a, *reinterpret_cast<const bf16x8*>(wz + 64 * j), az, 0, 0, 0);
                ar = __builtin_amdgcn_mfma_f32_16x16x32_bf16(
                    a, *reinterpret_cast<const bf16x8*>(wr + 64 * j), ar, 0, 0, 0);
                ah = __builtin_amdgcn_mfma_f32_16x16x32_bf16(
                    a, *reinterpret_cast<const bf16x8*>(wh + 64 * j), ah, 0, 0, 0);
            }
            const int tn = (t < T_ - 1) ? t + 1 : t;
            #pragma unroll
            for (int q = 0; q < 4; ++q)
                decn[q] = decays[(b_base + 4 * lk + q) * T_ + tn];
        } else {
            if (t > 0) {
                // gather-poll h(t) slice: rows b_base..+16, u in [(ks-1)*512, ks*512)
                const char* hbase = (const char*)(gbuf
                    + (size_t)(b_base + l15) * U_ + (ks - 1) * 512 + 8 * lk);
                bf16x8 hv[16];
                int guard = 0;
                for (;;) {
                    ISSUE16(hv, hbase)
                    WAITV0; PIN16(hv)
                    int un = 0;
                    #pragma unroll
                    for (int j = 0; j < 16; ++j) {
                        const u32x4 d = __builtin_bit_cast(u32x4, hv[j]);
                        un |= (d[0] == SENT) | (d[1] == SENT) |
                              (d[2] == SENT) | (d[3] == SENT);
                    }
                    if (!__any(un)) break;
                    if (++guard > POLL_LIM) break;   // safety: no hang
                    asm volatile("s_sleep 1");       // back off: cut L3 congestion
                }
                // 3-gate partial GEMM over this u-half
                #pragma unroll 4
                for (int j = 0; j < 16; ++j) {
                    const int o = 1024 * ks + 64 * j;
                    az = __builtin_amdgcn_mfma_f32_16x16x32_bf16(
                        hv[j], *reinterpret_cast<const bf16x8*>(wz + o), az, 0, 0, 0);
                    ar = __builtin_amdgcn_mfma_f32_16x16x32_bf16(
                        hv[j], *reinterpret_cast<const bf16x8*>(wr + o), ar, 0, 0, 0);
                    ah = __builtin_amdgcn_mfma_f32_16x16x32_bf16(
                        hv[j], *reinterpret_cast<const bf16x8*>(wh + o), ah, 0, 0, 0);
                }
            }
            // exchange partials
            char* e = lds + EXCH_OFF + (size_t)((bt * 2 + (ks - 1)) * 3) * 1024;
            *reinterpret_cast<f32x4*>(e + 0 * 1024 + lane * 16) = az;
            *reinterpret_cast<f32x4*>(e + 1 * 1024 + lane * 16) = ar;
            *reinterpret_cast<f32x4*>(e + 2 * 1024 + lane * 16) = ah;
        }

        __syncthreads();   // B2: partials ready; all this block's gathers done

        f32x4 sz, sr, sh;
        if (ks == 0) {
            // poison own tile of obuf FIRST (fire-and-forget; lands during
            // sum+epilogue, so the pre-publish vmcnt(0) is ~free).
            // Safe: B2 passed => this block read h(t) fully => all group
            // blocks finished their step-(t-1) reads of obuf's old contents.
            if (t < T_ - 1 && (lane & 1) == 0) {
                #pragma unroll
                for (int q = 0; q < 4; ++q) {
                    unsigned int* pa = (unsigned int*)(obuf
                        + (size_t)(b_base + 4 * lk + q) * U_ + u);
                    STORE_DW_AGENT(pa, SENT);
                }
            }
            const char* e0 = lds + EXCH_OFF + (size_t)((bt * 2 + 0) * 3) * 1024;
            const char* e1 = lds + EXCH_OFF + (size_t)((bt * 2 + 1) * 3) * 1024;
            sz = *reinterpret_cast<const f32x4*>(e0 + 0 * 1024 + lane * 16)
               + *reinterpret_cast<const f32x4*>(e1 + 0 * 1024 + lane * 16);
            sr = *reinterpret_cast<const f32x4*>(e0 + 1 * 1024 + lane * 16)
               + *reinterpret_cast<const f32x4*>(e1 + 1 * 1024 + lane * 16);
            sh = *reinterpret_cast<const f32x4*>(e0 + 2 * 1024 + lane * 16)
               + *reinterpret_cast<const f32x4*>(e1 + 2 * 1024 + lane * 16);
        }

        __syncthreads();   // B3: exf free for next step's writers

        if (ks == 0) {
            // epilogue
            float hn[4];
            #pragma unroll
            for (int q = 0; q < 4; ++q) {
                const float z  = 1.0f / (1.0f + expf(-(az[q] + sz[q] + bzs)));
                const float r  = 1.0f / (1.0f + expf(-(ar[q] + sr[q] + brs)));
                const float hh = tanhf(ah[q] + ibh_ + r * (sh[q] + rbh_));
                hn[q] = z * hreg[q] + (1.0f - z) * hh;
            }
            if (t == T_ - 1) {
                #pragma unroll
                for (int q = 0; q < 4; ++q)
                    out[(size_t)(b_base + 4 * lk + q) * U_ + u] = hn[q];
            } else {
                unsigned int pk[4];
                #pragma unroll
                for (int q = 0; q < 4; ++q) {
                    const float hd = hn[q] * decn[q];
                    hreg[q] = hd;
                    const float po = __shfl_xor(hd, 1);   // partner u (odd lane)
                    pk[q] = (unsigned int)f2bf(hd) | ((unsigned int)f2bf(po) << 16);
                }
                WAITV0;   // poison (issued pre-sum) visible before publish
                if ((lane & 1) == 0) {
                    #pragma unroll
                    for (int q = 0; q < 4; ++q) {
                        unsigned int* pa = (unsigned int*)(pbuf
                            + (size_t)(b_base + 4 * lk + q) * U_ + u);
                        STORE_DW_AGENT(pa, pk[q]);
                    }
                }
                // no vmcnt, no flag: the data itself is the signal.
            }
        }
    }
}

extern "C" void kernel_launch(void* const* d_in, const int* in_sizes, int n_in,
                              void* d_out, int out_size, void* d_ws, size_t ws_size,
                              hipStream_t stream) {
    const float* seq = (const float*)d_in[0];
    const float* dts = (const float*)d_in[1];
    const float* Wk  = (const float*)d_in[2];
    const float* Wr  = (const float*)d_in[3];
    const float* ib  = (const float*)d_in[4];
    const float* rb  = (const float*)d_in[5];
    float* out = (float*)d_out;

    char* wsb = (char*)d_ws;
    // ws layout (bytes):
    //   [0,        9437184)   WcatT bf16 [3072][1536]
    //   [9437184,  9568256)   decays fp32 [128][256]
    //   [9568256,  9830400)   hb0 bf16 [128][1024]
    //   [9830400, 10092544)   hb1
    //   [10092544,10354688)   hb2
    unsigned short* wcat   = (unsigned short*)(wsb);
    float*          decays = (float*)(wsb + 9437184);
    unsigned short* hb0    = (unsigned short*)(wsb + 9568256);
    unsigned short* hb1    = (unsigned short*)(wsb + 9830400);
    unsigned short* hb2    = (unsigned short*)(wsb + 10092544);

    wprep<<<dim3(K_TOT / 32, N3U / 32), dim3(32, 8), 0, stream>>>(Wk, Wr, wcat);
    // decays + poison all three h buffers (every launch/replay)
    dprep<<<dim3(384), dim3(256), 0, stream>>>(dts, decays, (unsigned int*)hb0);

    hipFuncSetAttribute((const void*)tgru_sent2,
                        hipFuncAttributeMaxDynamicSharedMemorySize, LDS_BYTES);

    tgru_sent2<<<dim3(256), dim3(384), LDS_BYTES, stream>>>(
        seq, decays, wcat, ib, rb, hb0, hb1, hb2, out);
}